// Round 11
// baseline (199.569 us; speedup 1.0000x reference)
//
#include <hip/hip_runtime.h>

// CIN (xDeepFM) fully-fused kernel for MI355X.
// B=4096, F=32, D=32; layer1: K1=1024 -> N=128; layer2: K2=4096 -> N=128.
// GEMM rows=(b,d); A generated in registers: A[(b,d)][h*M+m] = x0[b,h,d]*prev[b,m,d].
// mfma_f32_32x32x16_f16. Wave tile 4b x 64n (rt=4, ct=2): B-loads/MFMA=0.25
// (L1-safe), pk_mul/MFMA=2 (issue-safe), acc=128 AGPR -> 2 waves/SIMD.
// R11: de-bubbling. L1-B preloads hoisted above the staging barrier; L2-B
// preloads + x re-reads issued before the pre-epilogue barrier; P shadow-
// prefetched 2 p-iters ahead of each mc boundary (mc-pair ping-pong, no movs);
// XCD-aware block swizzle for x/L2 locality.

typedef _Float16 half_t;
typedef _Float16 half4v __attribute__((ext_vector_type(4)));
typedef _Float16 half8 __attribute__((ext_vector_type(8)));
typedef float f32x16 __attribute__((ext_vector_type(16)));

// ---- W pack (both filters, one launch): Wp[s][tg][n][8], k=h*M+mc*16+tg*8+j.
__global__ void prep_w_kernel(const float* __restrict__ W0,
                              const float* __restrict__ W1,
                              half_t* __restrict__ Wp0,
                              half_t* __restrict__ Wp1) {
  int gid = blockIdx.x * 256 + threadIdx.x;  // 320*256 threads
  int n = gid & 127;
  int tg = (gid >> 7) & 1;
  int s = gid >> 8;  // 0..319
  const float* W;
  half_t* Wp;
  int M, sl;
  if (s < 64) { W = W0; Wp = Wp0; M = 32; sl = s; }
  else        { W = W1; Wp = Wp1; M = 128; sl = s - 64; }
  int h = sl & 31, mc = sl >> 5;
  int kbase = h * M + mc * 16 + tg * 8;
  half8 v;
#pragma unroll
  for (int j = 0; j < 8; ++j) v[j] = (half_t)W[(size_t)(kbase + j) * 128 + n];
  *(half8*)(Wp + ((size_t)(sl * 2 + tg) * 128 + n) * 8) = v;
}

// swizzled prevT index: logical (row, m) -> halfs offset. 16B-chunk XOR spread.
__device__ __forceinline__ int pswz(int row, int m) {
  return row * 128 + (((m >> 3) ^ (row & 15)) << 3) + (m & 7);
}

__device__ __forceinline__ f32x16 mfma3216(half8 a, half8 b, f32x16 c) {
  return __builtin_amdgcn_mfma_f32_32x32x16_f16(a, b, c, 0, 0, 0);
}

template <bool L1>
__device__ __forceinline__ half8 p_read(const half_t* __restrict__ psrc,
                                        int row, int m) {
  return L1 ? *(const half8*)&psrc[row * 40 + m]
            : *(const half8*)&psrc[pswz(row, m)];
}

// One mc pass (16 p... 8 p-iters of 2 gg). Pc = current P; Pn = shadow for
// next mc, prefetched at p==5 when hasNext.
template <int MC, bool L1>
__device__ __forceinline__ void mc_pass(
    const half_t* __restrict__ Wp, const half_t* __restrict__ psrc,
    const half_t* __restrict__ xQw, int woff0, int woff1, int rowb, int l31,
    int hi, f32x16 acc[4][2], half8& B0a0, half8& B0a1, half8& B1a0,
    half8& B1a1, half8& B0b0, half8& B0b1, half8& B1b0, half8& B1b1,
    half8& xqa, half8& xqb, half8 Pc[4], half8 Pn[4], int mc, bool hasNext) {
#pragma unroll 1
  for (int p = 0; p < 8; ++p) {
    const int g0 = mc * 16 + 2 * p;  // even gg (global)
    // ---- even gg: consume ping ----
#pragma unroll
    for (int rt = 0; rt < 4; ++rt) {
      half8 Af = Pc[rt] * xqa[rt * 2 + 0];
      acc[rt][0] = mfma3216(Af, B0a0, acc[rt][0]);
      acc[rt][1] = mfma3216(Af, B0a1, acc[rt][1]);
    }
#pragma unroll
    for (int rt = 0; rt < 4; ++rt) {
      half8 Af = Pc[rt] * xqa[rt * 2 + 1];
      acc[rt][0] = mfma3216(Af, B1a0, acc[rt][0]);
      acc[rt][1] = mfma3216(Af, B1a1, acc[rt][1]);
    }
    {  // refill ping for g0+2
      const int sn = (2 * (g0 + 2)) & (MC * 32 - 1);
      B0a0 = *(const half8*)(Wp + (size_t)sn * 2048 + woff0);
      B0a1 = *(const half8*)(Wp + (size_t)sn * 2048 + woff1);
      B1a0 = *(const half8*)(Wp + (size_t)(sn + 1) * 2048 + woff0);
      B1a1 = *(const half8*)(Wp + (size_t)(sn + 1) * 2048 + woff1);
      xqa = *(const half8*)(xQw + ((2 * p + 2) & 15) * 256);
    }
    // ---- odd gg: consume pong ----
#pragma unroll
    for (int rt = 0; rt < 4; ++rt) {
      half8 Af = Pc[rt] * xqb[rt * 2 + 0];
      acc[rt][0] = mfma3216(Af, B0b0, acc[rt][0]);
      acc[rt][1] = mfma3216(Af, B0b1, acc[rt][1]);
    }
#pragma unroll
    for (int rt = 0; rt < 4; ++rt) {
      half8 Af = Pc[rt] * xqb[rt * 2 + 1];
      acc[rt][0] = mfma3216(Af, B1b0, acc[rt][0]);
      acc[rt][1] = mfma3216(Af, B1b1, acc[rt][1]);
    }
    {  // refill pong for g0+3
      const int sn = (2 * (g0 + 3)) & (MC * 32 - 1);
      B0b0 = *(const half8*)(Wp + (size_t)sn * 2048 + woff0);
      B0b1 = *(const half8*)(Wp + (size_t)sn * 2048 + woff1);
      B1b0 = *(const half8*)(Wp + (size_t)(sn + 1) * 2048 + woff0);
      B1b1 = *(const half8*)(Wp + (size_t)(sn + 1) * 2048 + woff1);
      xqb = *(const half8*)(xQw + ((2 * p + 3) & 15) * 256);
    }
    if (p == 5 && hasNext) {  // shadow-prefetch next-mc P (lead ~2 p-iters)
      const int mn = (mc + 1) * 16 + hi * 8;
#pragma unroll
      for (int rt = 0; rt < 4; ++rt)
        Pn[rt] = p_read<L1>(psrc, rowb + rt * 32 + l31, mn);
    }
  }
}

// One CIN layer: MC/2 mc-pairs with P ping-pong (zero movs). Caller preloads
// B ping-pong (s=0..3), xqa/xqb (gg=0,1) and Pc (mc=0).
template <int MC, bool L1>
__device__ __forceinline__ void layer_loop(
    const half_t* __restrict__ Wp, const half_t* __restrict__ psrc,
    const half_t* __restrict__ xQw, int woff0, int woff1, int rowb, int l31,
    int hi, f32x16 acc[4][2], half8& B0a0, half8& B0a1, half8& B1a0,
    half8& B1a1, half8& B0b0, half8& B0b1, half8& B1b0, half8& B1b1,
    half8& xqa, half8& xqb, half8 P[4], half8 Pn[4]) {
#pragma unroll 1
  for (int mcp = 0; mcp < MC / 2; ++mcp) {
    mc_pass<MC, L1>(Wp, psrc, xQw, woff0, woff1, rowb, l31, hi, acc, B0a0,
                    B0a1, B1a0, B1a1, B0b0, B0b1, B1b0, B1b1, xqa, xqb, P, Pn,
                    2 * mcp, true);
    mc_pass<MC, L1>(Wp, psrc, xQw, woff0, woff1, rowb, l31, hi, acc, B0a0,
                    B0a1, B1a0, B1a1, B0b0, B0b1, B1b0, B1b1, xqa, xqb, Pn, P,
                    2 * mcp + 1, 2 * mcp + 2 < MC);
  }
}

__global__ __launch_bounds__(256, 2) void cin_fused_kernel(
    const float* __restrict__ x0,    // [4096][32][32] fp32
    const half_t* __restrict__ Wp0,  // 64*2048 halfs
    const half_t* __restrict__ Wp1,  // 256*2048 halfs
    float* __restrict__ out) {       // [4096][256]
  __shared__ half_t xQ[2 * 16 * 32 * 8];  // [quad][hp][d][rtl*2+(h&1)] (16 KB)
  __shared__ half_t prevT[8 * 32 * 128];  // swizzled [bi][d][m] (64 KB); alias xT
  half_t* xT = prevT;                     // [bi*32+d][h], stride 40 halfs

  const int tid = threadIdx.x;
  // XCD swizzle: blocks on one XCD cover a contiguous 512-b range.
  const int bsw = (blockIdx.x & 7) * 64 + (blockIdx.x >> 3);
  const int b0 = bsw * 8;

  const int lane = tid & 63;
  const int l31 = lane & 31;
  const int hi = lane >> 5;
  const int wave = tid >> 6;
  const int wr = wave >> 1;  // b-quad: b's wr*4 .. wr*4+3
  const int wc = wave & 1;   // col half: n in [wc*64, wc*64+64)

  const int woff0 = hi * 1024 + (wc * 64 + l31) * 8;       // ct=0 B offset
  const int woff1 = hi * 1024 + (wc * 64 + 32 + l31) * 8;  // ct=1 B offset
  const int rowb = wr * 128;                               // P row base
  const half_t* xQw = xQ + wr * 4096 + l31 * 8;

  // ---- preload layer-1 B ping-pong (independent of LDS; before barrier) ----
  half8 B0a0 = *(const half8*)(Wp0 + 0 * 2048 + woff0);
  half8 B0a1 = *(const half8*)(Wp0 + 0 * 2048 + woff1);
  half8 B1a0 = *(const half8*)(Wp0 + 1 * 2048 + woff0);
  half8 B1a1 = *(const half8*)(Wp0 + 1 * 2048 + woff1);
  half8 B0b0 = *(const half8*)(Wp0 + 2 * 2048 + woff0);
  half8 B0b1 = *(const half8*)(Wp0 + 2 * 2048 + woff1);
  half8 B1b0 = *(const half8*)(Wp0 + 3 * 2048 + woff0);
  half8 B1b1 = *(const half8*)(Wp0 + 3 * 2048 + woff1);

  // ---- stage x0 -> xQ and xT (8 b = 8192 floats = 2048 float4) ----
  const float4* x4 = (const float4*)(x0 + (size_t)b0 * 1024);
#pragma unroll
  for (int r = 0; r < 8; ++r) {
    int q = r * 256 + tid;
    float4 v = x4[q];
    int e4 = q * 4;
    int bi = e4 >> 10, h = (e4 >> 5) & 31, d0 = e4 & 31;
    half4v hv = {(half_t)v.x, (half_t)v.y, (half_t)v.z, (half_t)v.w};
    const int quad = bi >> 2, rtl = bi & 3;
#pragma unroll
    for (int j = 0; j < 4; ++j) {
      xQ[quad * 4096 + (h >> 1) * 256 + (d0 + j) * 8 + rtl * 2 + (h & 1)] =
          hv[j];
      xT[(bi * 32 + d0 + j) * 40 + h] = hv[j];
    }
  }
  __syncthreads();

  half8 xqa = *(const half8*)(xQw);
  half8 xqb = *(const half8*)(xQw + 256);
  half8 P[4], Pn[4];
#pragma unroll
  for (int rt = 0; rt < 4; ++rt)
    P[rt] = p_read<true>(xT, rowb + rt * 32 + l31, hi * 8);

  f32x16 acc[4][2];
#pragma unroll
  for (int rt = 0; rt < 4; ++rt)
#pragma unroll
    for (int ct = 0; ct < 2; ++ct)
#pragma unroll
      for (int r = 0; r < 16; ++r) acc[rt][ct][r] = 0.f;

  // ================= layer 1 =================
  layer_loop<2, true>(Wp0, xT, xQw, woff0, woff1, rowb, l31, hi, acc, B0a0,
                      B0a1, B1a0, B1a1, B0b0, B0b1, B1b0, B1b1, xqa, xqb, P,
                      Pn);

  // ---- preload layer-2 B + x while epilogue/barrier run ----
  B0a0 = *(const half8*)(Wp1 + 0 * 2048 + woff0);
  B0a1 = *(const half8*)(Wp1 + 0 * 2048 + woff1);
  B1a0 = *(const half8*)(Wp1 + 1 * 2048 + woff0);
  B1a1 = *(const half8*)(Wp1 + 1 * 2048 + woff1);
  B0b0 = *(const half8*)(Wp1 + 2 * 2048 + woff0);
  B0b1 = *(const half8*)(Wp1 + 2 * 2048 + woff1);
  B1b0 = *(const half8*)(Wp1 + 3 * 2048 + woff0);
  B1b1 = *(const half8*)(Wp1 + 3 * 2048 + woff1);
  xqa = *(const half8*)(xQw);
  xqb = *(const half8*)(xQw + 256);

  __syncthreads();  // all waves done reading xT before prevT overwrite

  // ---- epilogue 1: relu, cur1 -> prevT (swizzled), d-sum -> out[:, 0:128] --
#pragma unroll
  for (int rt = 0; rt < 4; ++rt) {
#pragma unroll
    for (int ct = 0; ct < 2; ++ct) {
      float s = 0.f;
#pragma unroll
      for (int r = 0; r < 16; ++r) {
        float v = acc[rt][ct][r];
        v = v > 0.f ? v : 0.f;
        s += v;
        int d = (r & 3) + ((r >> 2) << 3) + hi * 4;  // C/D row map (32x32)
        prevT[pswz(rowb + rt * 32 + d, wc * 64 + ct * 32 + l31)] = (half_t)v;
        acc[rt][ct][r] = 0.f;
      }
      s += __shfl_down(s, 32);
      if (lane < 32)
        out[(size_t)(b0 + wr * 4 + rt) * 256 + wc * 64 + ct * 32 + lane] = s;
    }
  }
  __syncthreads();

#pragma unroll
  for (int rt = 0; rt < 4; ++rt)
    P[rt] = p_read<false>(prevT, rowb + rt * 32 + l31, hi * 8);

  // ================= layer 2 =================
  layer_loop<8, false>(Wp1, prevT, xQw, woff0, woff1, rowb, l31, hi, acc,
                       B0a0, B0a1, B1a0, B1a1, B0b0, B0b1, B1b0, B1b1, xqa,
                       xqb, P, Pn);

  // ---- epilogue 2: relu, d-sum -> out[:, 128:256] ----
#pragma unroll
  for (int rt = 0; rt < 4; ++rt) {
#pragma unroll
    for (int ct = 0; ct < 2; ++ct) {
      float s = 0.f;
#pragma unroll
      for (int r = 0; r < 16; ++r) {
        float v = acc[rt][ct][r];
        s += v > 0.f ? v : 0.f;
      }
      s += __shfl_down(s, 32);
      if (lane < 32)
        out[(size_t)(b0 + wr * 4 + rt) * 256 + 128 + wc * 64 + ct * 32 +
            lane] = s;
    }
  }
}

extern "C" void kernel_launch(void* const* d_in, const int* in_sizes, int n_in,
                              void* d_out, int out_size, void* d_ws,
                              size_t ws_size, hipStream_t stream) {
  const float* x0 = (const float*)d_in[0];  // [4096,32,32]
  const float* w0 = (const float*)d_in[1];  // [1,1024,128]
  const float* w1 = (const float*)d_in[2];  // [1,4096,128]
  float* out = (float*)d_out;               // [4096,256]
  char* ws = (char*)d_ws;

  half_t* Wp0 = (half_t*)(ws);                  // 64*2048 f16 = 256 KB
  half_t* Wp1 = (half_t*)(ws + 64 * 2048 * 2);  // 256*2048 f16 = 1 MB

  hipLaunchKernelGGL(prep_w_kernel, dim3(320), dim3(256), 0, stream, w0, w1,
                     Wp0, Wp1);
  hipLaunchKernelGGL(cin_fused_kernel, dim3(512), dim3(256), 0, stream, x0,
                     Wp0, Wp1, out);
}